// Round 16
// baseline (87.851 us; speedup 1.0000x reference)
//
#include <hip/hip_runtime.h>
#include <stdint.h>

#define HEADS 32
#define HW_N 1024
#define QS 0.36067376022224085f   // 0.25 * log2(e)
#define LOG2E 1.4426950408889634f

typedef __attribute__((ext_vector_type(8))) __bf16 bf16x8;
typedef __attribute__((ext_vector_type(4))) float f32x4;
typedef __attribute__((ext_vector_type(16))) float f32x16;
typedef __attribute__((ext_vector_type(4))) uint32_t u32x4;

__device__ __forceinline__ float b2f(uint16_t u) {
  union { uint32_t i; float f; } v; v.i = ((uint32_t)u) << 16; return v.f;
}
__device__ __forceinline__ uint16_t f2b(float f) {
  uint32_t u = __builtin_bit_cast(uint32_t, f);
  return (uint16_t)((u + 0x7FFFu + ((u >> 16) & 1u)) >> 16);
}

#define GLD16(g, s) __builtin_amdgcn_global_load_lds( \
    (const __attribute__((address_space(1))) void*)(g), \
    (__attribute__((address_space(3))) void*)(s), 16, 0, 0)

// ---------------- prep: f32->bf16 converts + bf16 bias tiles in MFMA C-layout ----------------
__global__ __launch_bounds__(256) void prep(const float* __restrict__ x,
                                            const float* __restrict__ wqv,
                                            const float* __restrict__ pw,
                                            const float* __restrict__ abias,
                                            uint16_t* __restrict__ xb,
                                            uint16_t* __restrict__ wqb,
                                            uint16_t* __restrict__ pwb,
                                            uint16_t* __restrict__ bt2b) {
  const int blk = blockIdx.x;
  const int tid = threadIdx.x;
  if (blk < 3584) {
    const float* in; uint16_t* out; int i;
    if (blk < 2048)      { in = x;   out = xb;  i = blk * 256 + tid; }
    else if (blk < 3072) { in = wqv; out = wqb; i = (blk - 2048) * 256 + tid; }
    else                 { in = pw;  out = pwb; i = (blk - 3072) * 256 + tid; }
    float4 v = ((const float4*)in)[i];
    ushort4 o;
    o.x = f2b(v.x); o.y = f2b(v.y); o.z = f2b(v.z); o.w = f2b(v.w);
    ((ushort4*)out)[i] = o;
  } else {
    __shared__ float rv[63];
    const int blk2 = blk - 3584;           // 0..2015
    const int h = blk2 / 63, d31 = blk2 - h * 63;
    if (tid < 63) rv[tid] = LOG2E * abias[(size_t)(d31 * 63 + tid) * 32 + h];
    __syncthreads();
    const size_t tb = ((size_t)(h * 63 + d31)) << 10;
#pragma unroll
    for (int c = 0; c < 4; ++c) {
      const int idx = c * 256 + tid;       // lane*16 + r
      const int lane = idx >> 4, r = idx & 15;
      const int hi = lane >> 5, ln = lane & 31;
      const int crow = (r & 3) + 8 * (r >> 2) + 4 * hi;
      const int col = 31 + ln - crow;      // 0..62
      bt2b[tb + idx] = f2b(rv[col]);
    }
  }
}

// ---------------- QKV projection GEMM: [4096,512] x [2048,512]^T, 128x64 tiles ----------------
__global__ __launch_bounds__(256) void gemm_qkv(
    const uint16_t* __restrict__ Aop, const uint16_t* __restrict__ Bop,
    uint16_t* __restrict__ qT, uint16_t* __restrict__ ko, uint16_t* __restrict__ vo) {
  const int K = 512;
  __shared__ uint16_t As[2][128 * 32];
  __shared__ uint16_t Bs[2][64 * 32];
  const int tid = threadIdx.x;
  const int lane = tid & 63;
  const int wave = tid >> 6;
  const int am0 = blockIdx.y * 128;
  const int bn0 = blockIdx.x * 64;
  const int wr = wave >> 1, wc = wave & 1;
  const int sc = (tid & 3) << 3;

  auto stage = [&](int buf, int kt) {
    const int k0 = kt << 5;
    GLD16(Aop + (size_t)(am0 + (tid >> 2)) * K + (k0 + sc), &As[buf][tid * 8]);
    GLD16(Aop + (size_t)(am0 + 64 + (tid >> 2)) * K + (k0 + sc), &As[buf][(tid + 256) * 8]);
    GLD16(Bop + (size_t)(bn0 + (tid >> 2)) * K + (k0 + sc), &Bs[buf][tid * 8]);
  };

  f32x4 acc[4][2] = {};
  stage(0, 0);
  asm volatile("s_waitcnt vmcnt(0)" ::: "memory");
  __syncthreads();

  const int fr = lane & 15;
  const int fk = (lane >> 4) << 3;
  int cur = 0;
  for (int kt = 0; kt < 16; ++kt) {
    if (kt + 1 < 16) stage(cur ^ 1, kt + 1);
    bf16x8 af[4], bf_[2];
#pragma unroll
    for (int mi = 0; mi < 4; ++mi)
      af[mi] = *(const bf16x8*)&As[cur][(wr * 64 + mi * 16 + fr) * 32 + fk];
#pragma unroll
    for (int ni = 0; ni < 2; ++ni)
      bf_[ni] = *(const bf16x8*)&Bs[cur][(wc * 32 + ni * 16 + fr) * 32 + fk];
#pragma unroll
    for (int mi = 0; mi < 4; ++mi)
#pragma unroll
      for (int ni = 0; ni < 2; ++ni)
        acc[mi][ni] = __builtin_amdgcn_mfma_f32_16x16x32_bf16(af[mi], bf_[ni], acc[mi][ni], 0, 0, 0);
    asm volatile("s_waitcnt vmcnt(0)" ::: "memory");
    __syncthreads();
    cur ^= 1;
  }

  const int rb = (lane >> 4) << 2;
  const int cl = lane & 15;
  const int b = am0 >> 10;
  const int h = blockIdx.x;
  const int bh = b * 32 + h;
#pragma unroll
  for (int mi = 0; mi < 4; ++mi) {
    const int n0 = (am0 & 1023) + wr * 64 + mi * 16 + rb;
    if (wc == 0) {
      {  // q transposed + pre-scaled
        ushort4 o;
        o.x = f2b(acc[mi][0][0] * QS); o.y = f2b(acc[mi][0][1] * QS);
        o.z = f2b(acc[mi][0][2] * QS); o.w = f2b(acc[mi][0][3] * QS);
        *(ushort4*)&qT[((size_t)(bh * 16 + cl) << 10) + n0] = o;
      }
#pragma unroll
      for (int r = 0; r < 4; ++r)  // k row-major
        ko[((size_t)(bh * 1024 + n0 + r)) * 16 + cl] = f2b(acc[mi][1][r]);
    } else {
#pragma unroll
      for (int ni = 0; ni < 2; ++ni) {  // v channel-major (V^T)
        const int l = h * 32 + ni * 16 + cl;
        ushort4 o;
        o.x = f2b(acc[mi][ni][0]); o.y = f2b(acc[mi][ni][1]);
        o.z = f2b(acc[mi][ni][2]); o.w = f2b(acc[mi][ni][3]);
        *(ushort4*)&vo[((size_t)(b * 1024 + l) << 10) + n0] = o;
      }
    }
  }
}

// ---------------- depthwise 3x3 conv (SAME), channel-major in AND out ----------------
__global__ __launch_bounds__(256) void dwconv3x3(const uint16_t* __restrict__ vimg,
                                                 const float* __restrict__ kw,
                                                 uint16_t* __restrict__ vcv) {
  __shared__ float t[1024];
  const int bl = blockIdx.x;
  const int l = bl & 1023;
  const int tid = threadIdx.x;
  const uint16_t* src = vimg + (size_t)bl * 1024;
  {
    uint2 vv = ((const uint2*)src)[tid];
    t[tid * 4 + 0] = b2f((uint16_t)vv.x);
    t[tid * 4 + 1] = b2f((uint16_t)(vv.x >> 16));
    t[tid * 4 + 2] = b2f((uint16_t)vv.y);
    t[tid * 4 + 3] = b2f((uint16_t)(vv.y >> 16));
  }
  float w[9];
#pragma unroll
  for (int i = 0; i < 9; ++i) w[i] = kw[l * 9 + i];
  __syncthreads();
  uint16_t* dst = vcv + (size_t)bl * 1024;
#pragma unroll
  for (int i = 0; i < 4; ++i) {
    const int p = tid + i * 256;
    const int y = p >> 5, x = p & 31;
    float a = 0.f;
#pragma unroll
    for (int dy = 0; dy < 3; ++dy) {
      const int yy = y + dy - 1;
      if (yy < 0 || yy > 31) continue;
#pragma unroll
      for (int dx = 0; dx < 3; ++dx) {
        const int xx = x + dx - 1;
        if (xx < 0 || xx > 31) continue;
        a += t[yy * 32 + xx] * w[dy * 3 + dx];
      }
    }
    dst[p] = f2b(a);
  }
}

// ---------------- MFMA fused attention + hardswish ----------------
// r16: T3+T4 counted-vmcnt pipeline. 3-buffer K/V (stage superstep s+2 while
// computing s), 9-slot mod-9 bias ring. Per iter: vmcnt(3|2) [waves 0-1 issue
// 3 loads/superstep, waves 2-3 issue 2; leaves batch s+1 in flight, batch s
// guaranteed landed] -> s_barrier -> stage(s+2) -> compute(s). Stage is
// post-barrier so compute(s-1) (same buf mod 3) is done on all waves (WAR-
// safe). vmcnt(0) only at s=15. Math byte-identical to r13/r14/r15.
__global__ __launch_bounds__(256, 4) void attn_mfma(
    const uint16_t* __restrict__ qT, const uint16_t* __restrict__ kb,
    const uint16_t* __restrict__ vt, const uint16_t* __restrict__ bt2b,
    uint16_t* __restrict__ hsO) {
  __shared__ __align__(16) uint16_t Ks[3][2][512];
  __shared__ __align__(16) uint16_t Vs[3][2][1024];
  __shared__ __align__(16) uint16_t Bs[9 * 1024];
  __shared__ float inv_s[128];
  const int blk = blockIdx.x;
  const int bh = blk & 127;
  const int qtg = blk >> 7;   // 0..7
  const int b = bh >> 5, h = bh & 31;
  const int tid = threadIdx.x;
  const int wave = tid >> 6, lane = tid & 63;
  const int hi = lane >> 5, ln = lane & 31;

  const int q0 = qtg * 128 + wave * 32;
  const int qi0 = qtg * 4;
  const int qi = qi0 + wave;

  union { ushort u[8]; bf16x8 v; } qu;
#pragma unroll
  for (int j = 0; j < 8; ++j)
    qu.u[j] = qT[((size_t)(bh * 16 + hi * 8 + j) << 10) + q0 + ln];
  const bf16x8 qf = qu.v;

  // per-superstep per-thread staging issue counts: waves 0-1: K+V+B0 = 3;
  // waves 2-3: V+B1 = 2 (basis for the counted vmcnt below)
  auto stageKV = [&](int buf, int t2) {
    if (tid < 128) {
      const int tile = tid >> 6, j = tid & 63;
      GLD16(kb + ((size_t)bh * 1024 + (t2 + tile) * 32 + (j & 31)) * 16 + ((j >> 5) & 1) * 8,
            &Ks[buf][tile][j * 8]);
    }
    {
      const int tile = tid >> 7, j = tid & 127;
      GLD16(vt + (((size_t)b * 1024 + h * 32 + (j & 31)) << 10) + (t2 + tile) * 32 + ((j >> 5) & 1) * 8 + ((j >> 6) & 1) * 16,
            &Vs[buf][tile][j * 8]);
    }
  };
  auto stageB = [&](int d31, int half) {
    if ((tid >> 7) == half) {
      const int j = tid & 127;
      GLD16(bt2b + (((size_t)h * 63 + d31) << 10) + (j & 63) * 16 + ((j >> 6) & 1) * 8,
            &Bs[(d31 % 9) * 1024 + j * 8]);
    }
  };

  // prologue: supersteps 0,1 (KV tiles 0..3) + bias window d31 in [qi0+28, qi0+34]
  stageKV(0, 0);
  stageKV(1, 2);
  stageB(qi0 + 30, 0); stageB(qi0 + 31, 1);
  stageB(qi0 + 32, 0); stageB(qi0 + 33, 1);
  stageB(qi0 + 34, 0); stageB(qi0 + 28, 1);
  stageB(qi0 + 29, 0);
  asm volatile("s_waitcnt vmcnt(0)" ::: "memory");
  __builtin_amdgcn_s_barrier();

  f32x16 oacc = {};
  float ls0 = 0.f, ls1 = 0.f;
  int slotA = (qi + 31) % 9;

#define COMPUTE(kf, ca, cb, vf0, vf1) do {                            \
    f32x16 cc;                                                        \
    _Pragma("unroll")                                                 \
    for (int j = 0; j < 4; ++j) {                                     \
      const uint32_t ua = ca[j], ub = cb[j];                          \
      cc[2 * j]     = __builtin_bit_cast(float, ua << 16);            \
      cc[2 * j + 1] = __builtin_bit_cast(float, ua & 0xFFFF0000u);    \
      cc[8 + 2 * j]     = __builtin_bit_cast(float, ub << 16);        \
      cc[8 + 2 * j + 1] = __builtin_bit_cast(float, ub & 0xFFFF0000u);\
    }                                                                 \
    const f32x16 s_ = __builtin_amdgcn_mfma_f32_32x32x16_bf16(kf, qf, cc, 0, 0, 0); \
    float p[16];                                                      \
    _Pragma("unroll")                                                 \
    for (int r = 0; r < 16; ++r) p[r] = __builtin_amdgcn_exp2f(s_[r]); \
    _Pragma("unroll")                                                 \
    for (int r = 0; r < 8; ++r) { ls0 += p[r]; ls1 += p[r + 8]; }     \
    uint32_t w0, w1, w2, w3, w4, w5, w6, w7;                          \
    w0 = __builtin_amdgcn_perm(__builtin_bit_cast(uint32_t, p[1]),  __builtin_bit_cast(uint32_t, p[0]),  0x07060302u); \
    w1 = __builtin_amdgcn_perm(__builtin_bit_cast(uint32_t, p[3]),  __builtin_bit_cast(uint32_t, p[2]),  0x07060302u); \
    w2 = __builtin_amdgcn_perm(__builtin_bit_cast(uint32_t, p[5]),  __builtin_bit_cast(uint32_t, p[4]),  0x07060302u); \
    w3 = __builtin_amdgcn_perm(__builtin_bit_cast(uint32_t, p[7]),  __builtin_bit_cast(uint32_t, p[6]),  0x07060302u); \
    w4 = __builtin_amdgcn_perm(__builtin_bit_cast(uint32_t, p[9]),  __builtin_bit_cast(uint32_t, p[8]),  0x07060302u); \
    w5 = __builtin_amdgcn_perm(__builtin_bit_cast(uint32_t, p[11]), __builtin_bit_cast(uint32_t, p[10]), 0x07060302u); \
    w6 = __builtin_amdgcn_perm(__builtin_bit_cast(uint32_t, p[13]), __builtin_bit_cast(uint32_t, p[12]), 0x07060302u); \
    w7 = __builtin_amdgcn_perm(__builtin_bit_cast(uint32_t, p[15]), __builtin_bit_cast(uint32_t, p[14]), 0x07060302u); \
    asm("v_permlane32_swap_b32 %0, %1" : "+v"(w0), "+v"(w2));         \
    asm("v_permlane32_swap_b32 %0, %1" : "+v"(w1), "+v"(w3));         \
    asm("v_permlane32_swap_b32 %0, %1" : "+v"(w4), "+v"(w6));         \
    asm("v_permlane32_swap_b32 %0, %1" : "+v"(w5), "+v"(w7));         \
    const u32x4 a0u = {w0, w1, w2, w3};                               \
    const u32x4 a1u = {w4, w5, w6, w7};                               \
    oacc = __builtin_amdgcn_mfma_f32_32x32x16_bf16(                   \
        __builtin_bit_cast(bf16x8, a0u), vf0, oacc, 0, 0, 0);         \
    oacc = __builtin_amdgcn_mfma_f32_32x32x16_bf16(                   \
        __builtin_bit_cast(bf16x8, a1u), vf1, oacc, 0, 0, 0);         \
  } while (0)

  for (int s = 0; s < 16; ++s) {
    // wait: batch s landed (batch s+1 may stay in flight); drain fully at tail
    if (s == 15) {
      asm volatile("s_waitcnt vmcnt(0)" ::: "memory");
    } else if (wave < 2) {
      asm volatile("s_waitcnt vmcnt(3)" ::: "memory");
    } else {
      asm volatile("s_waitcnt vmcnt(2)" ::: "memory");
    }
    __builtin_amdgcn_s_barrier();
    if (s < 14) {
      stageKV((s + 2) % 3, 2 * s + 4);
      stageB(qi0 + 27 - 2 * s, 0);
      stageB(qi0 + 26 - 2 * s, 1);
    }
    const int cur = s % 3;
    const int slotB = slotA ? slotA - 1 : 8;
    __builtin_amdgcn_s_setprio(1);
    {  // tile 2s
      const bf16x8 kf  = *(const bf16x8*)&Ks[cur][0][lane * 8];
      const bf16x8 vf0 = *(const bf16x8*)&Vs[cur][0][lane * 8];
      const bf16x8 vf1 = *(const bf16x8*)&Vs[cur][0][512 + lane * 8];
      const u32x4 ca = *(const u32x4*)&Bs[slotA * 1024 + lane * 8];
      const u32x4 cb = *(const u32x4*)&Bs[slotA * 1024 + 512 + lane * 8];
      COMPUTE(kf, ca, cb, vf0, vf1);
    }
    {  // tile 2s+1
      const bf16x8 kf  = *(const bf16x8*)&Ks[cur][1][lane * 8];
      const bf16x8 vf0 = *(const bf16x8*)&Vs[cur][1][lane * 8];
      const bf16x8 vf1 = *(const bf16x8*)&Vs[cur][1][512 + lane * 8];
      const u32x4 ca = *(const u32x4*)&Bs[slotB * 1024 + lane * 8];
      const u32x4 cb = *(const u32x4*)&Bs[slotB * 1024 + 512 + lane * 8];
      COMPUTE(kf, ca, cb, vf0, vf1);
    }
    __builtin_amdgcn_s_setprio(0);
    slotA = (slotA >= 2) ? slotA - 2 : slotA + 7;
  }
#undef COMPUTE

  const float lsum = ls0 + ls1;
  const float tot = lsum + __shfl_xor(lsum, 32);
  if (hi == 0) inv_s[wave * 32 + ln] = __builtin_amdgcn_rcpf(tot);
  const int ROWS[16] = {0,1,2,3,8,9,10,11,16,17,18,19,24,25,26,27};
#pragma unroll
  for (int r = 0; r < 16; ++r) {
    const int row = ROWS[r] + 4 * hi;
    const float o = oacc[r] * inv_s[wave * 32 + row];
    const float hs = o * fminf(fmaxf(o + 3.f, 0.f), 6.f) * (1.f / 6.f);
    hsO[((size_t)(b * 1024 + q0 + row) << 10) + h * 32 + ln] = f2b(hs);
  }
}

// ---------------- output projection GEMM: [4096,1024] x [512,1024]^T, 64x64 tiles ----------------
__global__ __launch_bounds__(256) void gemm_proj(
    const uint16_t* __restrict__ Aop, const uint16_t* __restrict__ Bop,
    float* __restrict__ Cout, const float* __restrict__ bias) {
  const int K = 1024;
  __shared__ uint16_t As[2][64 * 32];
  __shared__ uint16_t Bs[2][64 * 32];
  const int tid = threadIdx.x;
  const int lane = tid & 63;
  const int wave = tid >> 6;
  const int am0 = blockIdx.y * 64;
  const int bn0 = blockIdx.x * 64;
  const int m_off = (wave >> 1) * 32;
  const int n_off = (wave & 1) * 32;
  const int sr = tid >> 2;
  const int sc = (tid & 3) << 3;

  auto stage = [&](int buf, int kt) {
    const int k0 = kt << 5;
    GLD16(Aop + (size_t)(am0 + sr) * K + (k0 + sc), &As[buf][tid * 8]);
    GLD16(Bop + (size_t)(bn0 + sr) * K + (k0 + sc), &Bs[buf][tid * 8]);
  };

  f32x4 acc[2][2] = {};
  stage(0, 0);
  asm volatile("s_waitcnt vmcnt(0)" ::: "memory");
  __syncthreads();

  const int fr = lane & 15;
  const int fk = (lane >> 4) << 3;
  int cur = 0;
  for (int kt = 0; kt < 32; ++kt) {
    if (kt + 1 < 32) stage(cur ^ 1, kt + 1);
    bf16x8 af[2], bf_[2];
#pragma unroll
    for (int mi = 0; mi < 2; ++mi)
      af[mi] = *(const bf16x8*)&As[cur][(m_off + mi * 16 + fr) * 32 + fk];
#pragma unroll
    for (int ni = 0; ni < 2; ++ni)
      bf_[ni] = *(const bf16x8*)&Bs[cur][(n_off + ni * 16 + fr) * 32 + fk];
#pragma unroll
    for (int mi = 0; mi < 2; ++mi)
#pragma unroll
      for (int ni = 0; ni < 2; ++ni)
        acc[mi][ni] = __builtin_amdgcn_mfma_f32_16x16x32_bf16(af[mi], bf_[ni], acc[mi][ni], 0, 0, 0);
    asm volatile("s_waitcnt vmcnt(0)" ::: "memory");
    __syncthreads();
    cur ^= 1;
  }

  const int rb = (lane >> 4) << 2;
  const int cl = lane & 15;
#pragma unroll
  for (int mi = 0; mi < 2; ++mi)
#pragma unroll
    for (int ni = 0; ni < 2; ++ni) {
      const int cg = bn0 + n_off + ni * 16 + cl;
#pragma unroll
      for (int r = 0; r < 4; ++r) {
        const int rg = am0 + m_off + mi * 16 + rb + r;
        Cout[(size_t)rg * 512 + cg] = acc[mi][ni][r] + bias[cg];
      }
    }
}

// ---------------- launch ----------------
extern "C" void kernel_launch(void* const* d_in, const int* in_sizes, int n_in,
                              void* d_out, int out_size, void* d_ws, size_t ws_size,
                              hipStream_t stream) {
  const float* x      = (const float*)d_in[0];
  const float* w_qkv  = (const float*)d_in[1];
  const float* dwk    = (const float*)d_in[2];
  const float* abias  = (const float*)d_in[3];
  const float* pw     = (const float*)d_in[4];
  const float* pb     = (const float*)d_in[5];
  float* out = (float*)d_out;

  char* ws = (char*)d_ws;
  uint16_t* xb   = (uint16_t*)(ws);                 // 4 MB
  uint16_t* wqb  = (uint16_t*)(ws + (4ull << 20));  // 2 MB
  uint16_t* pwb  = (uint16_t*)(ws + (6ull << 20));  // 1 MB
  uint16_t* qT   = (uint16_t*)(ws + (7ull << 20));  // 4 MB
  uint16_t* kbuf = (uint16_t*)(ws + (11ull << 20)); // 4 MB
  uint16_t* vimg = (uint16_t*)(ws + (15ull << 20)); // 8 MB (reused as hsO)
  uint16_t* vcv  = (uint16_t*)(ws + (23ull << 20)); // 8 MB (channel-major = V^T)
  uint16_t* bt2b = (uint16_t*)(ws + (31ull << 20)); // 4 MB bf16 bias tiles
  uint16_t* hsO  = vimg;

  prep<<<5600, 256, 0, stream>>>(x, w_qkv, pw, abias, xb, wqb, pwb, bt2b);
  gemm_qkv<<<dim3(32, 32), 256, 0, stream>>>(xb, wqb, qT, kbuf, vimg);
  dwconv3x3<<<4096, 256, 0, stream>>>(vimg, dwk, vcv);
  attn_mfma<<<1024, 256, 0, stream>>>(qT, kbuf, vcv, bt2b, hsO);
  gemm_proj<<<dim3(8, 64), 256, 0, stream>>>(hsO, pwb, out, pb);
}

// Round 17
// 84.012 us; speedup vs baseline: 1.0457x; 1.0457x over previous
//
#include <hip/hip_runtime.h>
#include <stdint.h>

#define HEADS 32
#define HW_N 1024
#define QS 0.36067376022224085f   // 0.25 * log2(e)
#define LOG2E 1.4426950408889634f

typedef __attribute__((ext_vector_type(8))) __bf16 bf16x8;
typedef __attribute__((ext_vector_type(4))) float f32x4;
typedef __attribute__((ext_vector_type(16))) float f32x16;
typedef __attribute__((ext_vector_type(4))) uint32_t u32x4;

__device__ __forceinline__ float b2f(uint16_t u) {
  union { uint32_t i; float f; } v; v.i = ((uint32_t)u) << 16; return v.f;
}
__device__ __forceinline__ uint16_t f2b(float f) {
  uint32_t u = __builtin_bit_cast(uint32_t, f);
  return (uint16_t)((u + 0x7FFFu + ((u >> 16) & 1u)) >> 16);
}

#define GLD16(g, s) __builtin_amdgcn_global_load_lds( \
    (const __attribute__((address_space(1))) void*)(g), \
    (__attribute__((address_space(3))) void*)(s), 16, 0, 0)

// ---------------- prep: f32->bf16 converts + bf16 bias tiles in MFMA C-layout ----------------
__global__ __launch_bounds__(256) void prep(const float* __restrict__ x,
                                            const float* __restrict__ wqv,
                                            const float* __restrict__ pw,
                                            const float* __restrict__ abias,
                                            uint16_t* __restrict__ xb,
                                            uint16_t* __restrict__ wqb,
                                            uint16_t* __restrict__ pwb,
                                            uint16_t* __restrict__ bt2b) {
  const int blk = blockIdx.x;
  const int tid = threadIdx.x;
  if (blk < 3584) {
    const float* in; uint16_t* out; int i;
    if (blk < 2048)      { in = x;   out = xb;  i = blk * 256 + tid; }
    else if (blk < 3072) { in = wqv; out = wqb; i = (blk - 2048) * 256 + tid; }
    else                 { in = pw;  out = pwb; i = (blk - 3072) * 256 + tid; }
    float4 v = ((const float4*)in)[i];
    ushort4 o;
    o.x = f2b(v.x); o.y = f2b(v.y); o.z = f2b(v.z); o.w = f2b(v.w);
    ((ushort4*)out)[i] = o;
  } else {
    __shared__ float rv[63];
    const int blk2 = blk - 3584;           // 0..2015
    const int h = blk2 / 63, d31 = blk2 - h * 63;
    if (tid < 63) rv[tid] = LOG2E * abias[(size_t)(d31 * 63 + tid) * 32 + h];
    __syncthreads();
    const size_t tb = ((size_t)(h * 63 + d31)) << 10;
#pragma unroll
    for (int c = 0; c < 4; ++c) {
      const int idx = c * 256 + tid;       // lane*16 + r
      const int lane = idx >> 4, r = idx & 15;
      const int hi = lane >> 5, ln = lane & 31;
      const int crow = (r & 3) + 8 * (r >> 2) + 4 * hi;
      const int col = 31 + ln - crow;      // 0..62
      bt2b[tb + idx] = f2b(rv[col]);
    }
  }
}

// ---------------- QKV projection GEMM: [4096,512] x [2048,512]^T, 128x64 tiles ----------------
__global__ __launch_bounds__(256) void gemm_qkv(
    const uint16_t* __restrict__ Aop, const uint16_t* __restrict__ Bop,
    uint16_t* __restrict__ qT, uint16_t* __restrict__ ko, uint16_t* __restrict__ vo) {
  const int K = 512;
  __shared__ uint16_t As[2][128 * 32];
  __shared__ uint16_t Bs[2][64 * 32];
  const int tid = threadIdx.x;
  const int lane = tid & 63;
  const int wave = tid >> 6;
  const int am0 = blockIdx.y * 128;
  const int bn0 = blockIdx.x * 64;
  const int wr = wave >> 1, wc = wave & 1;
  const int sc = (tid & 3) << 3;

  auto stage = [&](int buf, int kt) {
    const int k0 = kt << 5;
    GLD16(Aop + (size_t)(am0 + (tid >> 2)) * K + (k0 + sc), &As[buf][tid * 8]);
    GLD16(Aop + (size_t)(am0 + 64 + (tid >> 2)) * K + (k0 + sc), &As[buf][(tid + 256) * 8]);
    GLD16(Bop + (size_t)(bn0 + (tid >> 2)) * K + (k0 + sc), &Bs[buf][tid * 8]);
  };

  f32x4 acc[4][2] = {};
  stage(0, 0);
  asm volatile("s_waitcnt vmcnt(0)" ::: "memory");
  __syncthreads();

  const int fr = lane & 15;
  const int fk = (lane >> 4) << 3;
  int cur = 0;
  for (int kt = 0; kt < 16; ++kt) {
    if (kt + 1 < 16) stage(cur ^ 1, kt + 1);
    bf16x8 af[4], bf_[2];
#pragma unroll
    for (int mi = 0; mi < 4; ++mi)
      af[mi] = *(const bf16x8*)&As[cur][(wr * 64 + mi * 16 + fr) * 32 + fk];
#pragma unroll
    for (int ni = 0; ni < 2; ++ni)
      bf_[ni] = *(const bf16x8*)&Bs[cur][(wc * 32 + ni * 16 + fr) * 32 + fk];
#pragma unroll
    for (int mi = 0; mi < 4; ++mi)
#pragma unroll
      for (int ni = 0; ni < 2; ++ni)
        acc[mi][ni] = __builtin_amdgcn_mfma_f32_16x16x32_bf16(af[mi], bf_[ni], acc[mi][ni], 0, 0, 0);
    asm volatile("s_waitcnt vmcnt(0)" ::: "memory");
    __syncthreads();
    cur ^= 1;
  }

  const int rb = (lane >> 4) << 2;
  const int cl = lane & 15;
  const int b = am0 >> 10;
  const int h = blockIdx.x;
  const int bh = b * 32 + h;
#pragma unroll
  for (int mi = 0; mi < 4; ++mi) {
    const int n0 = (am0 & 1023) + wr * 64 + mi * 16 + rb;
    if (wc == 0) {
      {  // q transposed + pre-scaled
        ushort4 o;
        o.x = f2b(acc[mi][0][0] * QS); o.y = f2b(acc[mi][0][1] * QS);
        o.z = f2b(acc[mi][0][2] * QS); o.w = f2b(acc[mi][0][3] * QS);
        *(ushort4*)&qT[((size_t)(bh * 16 + cl) << 10) + n0] = o;
      }
#pragma unroll
      for (int r = 0; r < 4; ++r)  // k row-major
        ko[((size_t)(bh * 1024 + n0 + r)) * 16 + cl] = f2b(acc[mi][1][r]);
    } else {
#pragma unroll
      for (int ni = 0; ni < 2; ++ni) {  // v channel-major (V^T)
        const int l = h * 32 + ni * 16 + cl;
        ushort4 o;
        o.x = f2b(acc[mi][ni][0]); o.y = f2b(acc[mi][ni][1]);
        o.z = f2b(acc[mi][ni][2]); o.w = f2b(acc[mi][ni][3]);
        *(ushort4*)&vo[((size_t)(b * 1024 + l) << 10) + n0] = o;
      }
    }
  }
}

// ---------------- depthwise 3x3 conv (SAME), channel-major in AND out ----------------
__global__ __launch_bounds__(256) void dwconv3x3(const uint16_t* __restrict__ vimg,
                                                 const float* __restrict__ kw,
                                                 uint16_t* __restrict__ vcv) {
  __shared__ float t[1024];
  const int bl = blockIdx.x;
  const int l = bl & 1023;
  const int tid = threadIdx.x;
  const uint16_t* src = vimg + (size_t)bl * 1024;
  {
    uint2 vv = ((const uint2*)src)[tid];
    t[tid * 4 + 0] = b2f((uint16_t)vv.x);
    t[tid * 4 + 1] = b2f((uint16_t)(vv.x >> 16));
    t[tid * 4 + 2] = b2f((uint16_t)vv.y);
    t[tid * 4 + 3] = b2f((uint16_t)(vv.y >> 16));
  }
  float w[9];
#pragma unroll
  for (int i = 0; i < 9; ++i) w[i] = kw[l * 9 + i];
  __syncthreads();
  uint16_t* dst = vcv + (size_t)bl * 1024;
#pragma unroll
  for (int i = 0; i < 4; ++i) {
    const int p = tid + i * 256;
    const int y = p >> 5, x = p & 31;
    float a = 0.f;
#pragma unroll
    for (int dy = 0; dy < 3; ++dy) {
      const int yy = y + dy - 1;
      if (yy < 0 || yy > 31) continue;
#pragma unroll
      for (int dx = 0; dx < 3; ++dx) {
        const int xx = x + dx - 1;
        if (xx < 0 || xx > 31) continue;
        a += t[yy * 32 + xx] * w[dy * 3 + dx];
      }
    }
    dst[p] = f2b(a);
  }
}

// ---------------- MFMA fused attention + hardswish ----------------
// r15 version (best: 84.4 us total). 2-tile superstep, LDS-staged K/V/bias,
// 7-slot bias ring, setprio around compute. r16's counted-vmcnt variant
// REGRESSED (+3.5 us) - do not re-apply.
__global__ __launch_bounds__(256, 4) void attn_mfma(
    const uint16_t* __restrict__ qT, const uint16_t* __restrict__ kb,
    const uint16_t* __restrict__ vt, const uint16_t* __restrict__ bt2b,
    uint16_t* __restrict__ hsO) {
  __shared__ __align__(16) uint16_t Ks[2][2][512];
  __shared__ __align__(16) uint16_t Vs[2][2][1024];
  __shared__ __align__(16) uint16_t Bs[7 * 1024];
  __shared__ float inv_s[128];
  const int blk = blockIdx.x;
  const int bh = blk & 127;
  const int qtg = blk >> 7;
  const int b = bh >> 5, h = bh & 31;
  const int tid = threadIdx.x;
  const int wave = tid >> 6, lane = tid & 63;
  const int hi = lane >> 5, ln = lane & 31;

  const int q0 = qtg * 128 + wave * 32;
  const int qi0 = qtg * 4;
  const int qi = qi0 + wave;

  union { ushort u[8]; bf16x8 v; } qu;
#pragma unroll
  for (int j = 0; j < 8; ++j)
    qu.u[j] = qT[((size_t)(bh * 16 + hi * 8 + j) << 10) + q0 + ln];
  const bf16x8 qf = qu.v;

  auto stageKV = [&](int buf, int t2) {
    if (tid < 128) {
      const int tile = tid >> 6, j = tid & 63;
      GLD16(kb + ((size_t)bh * 1024 + (t2 + tile) * 32 + (j & 31)) * 16 + ((j >> 5) & 1) * 8,
            &Ks[buf][tile][j * 8]);
    }
    {
      const int tile = tid >> 7, j = tid & 127;
      GLD16(vt + (((size_t)b * 1024 + h * 32 + (j & 31)) << 10) + (t2 + tile) * 32 + ((j >> 5) & 1) * 8 + ((j >> 6) & 1) * 16,
            &Vs[buf][tile][j * 8]);
    }
  };
  auto stageB = [&](int d31, int half) {
    if ((tid >> 7) == half) {
      const int j = tid & 127;
      GLD16(bt2b + (((size_t)h * 63 + d31) << 10) + (j & 63) * 16 + ((j >> 6) & 1) * 8,
            &Bs[(d31 % 7) * 1024 + j * 8]);
    }
  };

  stageKV(0, 0);
  stageB(qi0 + 30, 0); stageB(qi0 + 31, 1);
  stageB(qi0 + 32, 0); stageB(qi0 + 33, 1);
  stageB(qi0 + 34, 0);
  __syncthreads();

  f32x16 oacc = {};
  float ls0 = 0.f, ls1 = 0.f;
  int cur = 0;
  int slotA = (qi + 31) % 7;

#define COMPUTE(kf, ca, cb, vf0, vf1) do {                            \
    f32x16 cc;                                                        \
    _Pragma("unroll")                                                 \
    for (int j = 0; j < 4; ++j) {                                     \
      const uint32_t ua = ca[j], ub = cb[j];                          \
      cc[2 * j]     = __builtin_bit_cast(float, ua << 16);            \
      cc[2 * j + 1] = __builtin_bit_cast(float, ua & 0xFFFF0000u);    \
      cc[8 + 2 * j]     = __builtin_bit_cast(float, ub << 16);        \
      cc[8 + 2 * j + 1] = __builtin_bit_cast(float, ub & 0xFFFF0000u);\
    }                                                                 \
    const f32x16 s = __builtin_amdgcn_mfma_f32_32x32x16_bf16(kf, qf, cc, 0, 0, 0); \
    float p[16];                                                      \
    _Pragma("unroll")                                                 \
    for (int r = 0; r < 16; ++r) p[r] = __builtin_amdgcn_exp2f(s[r]); \
    _Pragma("unroll")                                                 \
    for (int r = 0; r < 8; ++r) { ls0 += p[r]; ls1 += p[r + 8]; }     \
    uint32_t w0, w1, w2, w3, w4, w5, w6, w7;                          \
    w0 = __builtin_amdgcn_perm(__builtin_bit_cast(uint32_t, p[1]),  __builtin_bit_cast(uint32_t, p[0]),  0x07060302u); \
    w1 = __builtin_amdgcn_perm(__builtin_bit_cast(uint32_t, p[3]),  __builtin_bit_cast(uint32_t, p[2]),  0x07060302u); \
    w2 = __builtin_amdgcn_perm(__builtin_bit_cast(uint32_t, p[5]),  __builtin_bit_cast(uint32_t, p[4]),  0x07060302u); \
    w3 = __builtin_amdgcn_perm(__builtin_bit_cast(uint32_t, p[7]),  __builtin_bit_cast(uint32_t, p[6]),  0x07060302u); \
    w4 = __builtin_amdgcn_perm(__builtin_bit_cast(uint32_t, p[9]),  __builtin_bit_cast(uint32_t, p[8]),  0x07060302u); \
    w5 = __builtin_amdgcn_perm(__builtin_bit_cast(uint32_t, p[11]), __builtin_bit_cast(uint32_t, p[10]), 0x07060302u); \
    w6 = __builtin_amdgcn_perm(__builtin_bit_cast(uint32_t, p[13]), __builtin_bit_cast(uint32_t, p[12]), 0x07060302u); \
    w7 = __builtin_amdgcn_perm(__builtin_bit_cast(uint32_t, p[15]), __builtin_bit_cast(uint32_t, p[14]), 0x07060302u); \
    asm("v_permlane32_swap_b32 %0, %1" : "+v"(w0), "+v"(w2));         \
    asm("v_permlane32_swap_b32 %0, %1" : "+v"(w1), "+v"(w3));         \
    asm("v_permlane32_swap_b32 %0, %1" : "+v"(w4), "+v"(w6));         \
    asm("v_permlane32_swap_b32 %0, %1" : "+v"(w5), "+v"(w7));         \
    const u32x4 a0u = {w0, w1, w2, w3};                               \
    const u32x4 a1u = {w4, w5, w6, w7};                               \
    oacc = __builtin_amdgcn_mfma_f32_32x32x16_bf16(                   \
        __builtin_bit_cast(bf16x8, a0u), vf0, oacc, 0, 0, 0);         \
    oacc = __builtin_amdgcn_mfma_f32_32x32x16_bf16(                   \
        __builtin_bit_cast(bf16x8, a1u), vf1, oacc, 0, 0, 0);         \
  } while (0)

  for (int s = 0; s < 16; ++s) {
    if (s < 15) {
      stageKV(cur ^ 1, 2 * s + 2);
      stageB(qi0 + 29 - 2 * s, 0);
      stageB(qi0 + 28 - 2 * s, 1);
    }
    const int slotB = slotA ? slotA - 1 : 6;
    __builtin_amdgcn_s_setprio(1);
    {  // tile 2s
      const bf16x8 kf  = *(const bf16x8*)&Ks[cur][0][lane * 8];
      const bf16x8 vf0 = *(const bf16x8*)&Vs[cur][0][lane * 8];
      const bf16x8 vf1 = *(const bf16x8*)&Vs[cur][0][512 + lane * 8];
      const u32x4 ca = *(const u32x4*)&Bs[slotA * 1024 + lane * 8];
      const u32x4 cb = *(const u32x4*)&Bs[slotA * 1024 + 512 + lane * 8];
      COMPUTE(kf, ca, cb, vf0, vf1);
    }
    {  // tile 2s+1
      const bf16x8 kf  = *(const bf16x8*)&Ks[cur][1][lane * 8];
      const bf16x8 vf0 = *(const bf16x8*)&Vs[cur][1][lane * 8];
      const bf16x8 vf1 = *(const bf16x8*)&Vs[cur][1][512 + lane * 8];
      const u32x4 ca = *(const u32x4*)&Bs[slotB * 1024 + lane * 8];
      const u32x4 cb = *(const u32x4*)&Bs[slotB * 1024 + 512 + lane * 8];
      COMPUTE(kf, ca, cb, vf0, vf1);
    }
    __builtin_amdgcn_s_setprio(0);
    __syncthreads();
    cur ^= 1;
    slotA = (slotA >= 2) ? slotA - 2 : slotA + 5;
  }
#undef COMPUTE

  const float lsum = ls0 + ls1;
  const float tot = lsum + __shfl_xor(lsum, 32);
  if (hi == 0) inv_s[wave * 32 + ln] = __builtin_amdgcn_rcpf(tot);
  const int ROWS[16] = {0,1,2,3,8,9,10,11,16,17,18,19,24,25,26,27};
#pragma unroll
  for (int r = 0; r < 16; ++r) {
    const int row = ROWS[r] + 4 * hi;
    const float o = oacc[r] * inv_s[wave * 32 + row];
    const float hs = o * fminf(fmaxf(o + 3.f, 0.f), 6.f) * (1.f / 6.f);
    hsO[((size_t)(b * 1024 + q0 + row) << 10) + h * 32 + ln] = f2b(hs);
  }
}

// ---------------- output projection GEMM: [4096,1024] x [512,1024]^T ----------------
// r17: BK 32 -> 64 (16 k-iterations instead of 32; half the barrier drains,
// 8 MFMA per barrier). LDS 32 KB.
__global__ __launch_bounds__(256) void gemm_proj(
    const uint16_t* __restrict__ Aop, const uint16_t* __restrict__ Bop,
    float* __restrict__ Cout, const float* __restrict__ bias) {
  const int K = 1024;
  __shared__ uint16_t As[2][64 * 64];
  __shared__ uint16_t Bs[2][64 * 64];
  const int tid = threadIdx.x;
  const int lane = tid & 63;
  const int wave = tid >> 6;
  const int am0 = blockIdx.y * 64;
  const int bn0 = blockIdx.x * 64;
  const int m_off = (wave >> 1) * 32;
  const int n_off = (wave & 1) * 32;
  const int sr = tid >> 3;            // 0..31
  const int sc = (tid & 7) << 3;      // 0..56

  auto stage = [&](int buf, int kt) {
    const int k0 = kt << 6;
    GLD16(Aop + (size_t)(am0 + sr) * K + (k0 + sc), &As[buf][tid * 8]);
    GLD16(Aop + (size_t)(am0 + 32 + sr) * K + (k0 + sc), &As[buf][(tid + 256) * 8]);
    GLD16(Bop + (size_t)(bn0 + sr) * K + (k0 + sc), &Bs[buf][tid * 8]);
    GLD16(Bop + (size_t)(bn0 + 32 + sr) * K + (k0 + sc), &Bs[buf][(tid + 256) * 8]);
  };

  f32x4 acc[2][2] = {};
  stage(0, 0);
  asm volatile("s_waitcnt vmcnt(0)" ::: "memory");
  __syncthreads();

  const int fr = lane & 15;
  const int fk = (lane >> 4) << 3;
  int cur = 0;
  for (int kt = 0; kt < 16; ++kt) {
    if (kt + 1 < 16) stage(cur ^ 1, kt + 1);
#pragma unroll
    for (int kk = 0; kk < 2; ++kk) {
      bf16x8 af[2], bf_[2];
#pragma unroll
      for (int mi = 0; mi < 2; ++mi)
        af[mi] = *(const bf16x8*)&As[cur][(m_off + mi * 16 + fr) * 64 + kk * 32 + fk];
#pragma unroll
      for (int ni = 0; ni < 2; ++ni)
        bf_[ni] = *(const bf16x8*)&Bs[cur][(n_off + ni * 16 + fr) * 64 + kk * 32 + fk];
#pragma unroll
      for (int mi = 0; mi < 2; ++mi)
#pragma unroll
        for (int ni = 0; ni < 2; ++ni)
          acc[mi][ni] = __builtin_amdgcn_mfma_f32_16x16x32_bf16(af[mi], bf_[ni], acc[mi][ni], 0, 0, 0);
    }
    asm volatile("s_waitcnt vmcnt(0)" ::: "memory");
    __syncthreads();
    cur ^= 1;
  }

  const int rb = (lane >> 4) << 2;
  const int cl = lane & 15;
#pragma unroll
  for (int mi = 0; mi < 2; ++mi)
#pragma unroll
    for (int ni = 0; ni < 2; ++ni) {
      const int cg = bn0 + n_off + ni * 16 + cl;
#pragma unroll
      for (int r = 0; r < 4; ++r) {
        const int rg = am0 + m_off + mi * 16 + rb + r;
        Cout[(size_t)rg * 512 + cg] = acc[mi][ni][r] + bias[cg];
      }
    }
}

// ---------------- launch ----------------
extern "C" void kernel_launch(void* const* d_in, const int* in_sizes, int n_in,
                              void* d_out, int out_size, void* d_ws, size_t ws_size,
                              hipStream_t stream) {
  const float* x      = (const float*)d_in[0];
  const float* w_qkv  = (const float*)d_in[1];
  const float* dwk    = (const float*)d_in[2];
  const float* abias  = (const float*)d_in[3];
  const float* pw     = (const float*)d_in[4];
  const float* pb     = (const float*)d_in[5];
  float* out = (float*)d_out;

  char* ws = (char*)d_ws;
  uint16_t* xb   = (uint16_t*)(ws);                 // 4 MB
  uint16_t* wqb  = (uint16_t*)(ws + (4ull << 20));  // 2 MB
  uint16_t* pwb  = (uint16_t*)(ws + (6ull << 20));  // 1 MB
  uint16_t* qT   = (uint16_t*)(ws + (7ull << 20));  // 4 MB
  uint16_t* kbuf = (uint16_t*)(ws + (11ull << 20)); // 4 MB
  uint16_t* vimg = (uint16_t*)(ws + (15ull << 20)); // 8 MB (reused as hsO)
  uint16_t* vcv  = (uint16_t*)(ws + (23ull << 20)); // 8 MB (channel-major = V^T)
  uint16_t* bt2b = (uint16_t*)(ws + (31ull << 20)); // 4 MB bf16 bias tiles
  uint16_t* hsO  = vimg;

  prep<<<5600, 256, 0, stream>>>(x, w_qkv, pw, abias, xb, wqb, pwb, bt2b);
  gemm_qkv<<<dim3(32, 32), 256, 0, stream>>>(xb, wqb, qT, kbuf, vimg);
  dwconv3x3<<<4096, 256, 0, stream>>>(vimg, dwk, vcv);
  attn_mfma<<<1024, 256, 0, stream>>>(qT, kbuf, vcv, bt2b, hsO);
  gemm_proj<<<dim3(8, 64), 256, 0, stream>>>(hsO, pwb, out, pb);
}

// Round 18
// 83.966 us; speedup vs baseline: 1.0463x; 1.0005x over previous
//
#include <hip/hip_runtime.h>
#include <stdint.h>

#define HEADS 32
#define HW_N 1024
#define QS 0.36067376022224085f   // 0.25 * log2(e)
#define LOG2E 1.4426950408889634f

typedef __attribute__((ext_vector_type(8))) __bf16 bf16x8;
typedef __attribute__((ext_vector_type(4))) float f32x4;
typedef __attribute__((ext_vector_type(16))) float f32x16;
typedef __attribute__((ext_vector_type(4))) uint32_t u32x4;

__device__ __forceinline__ float b2f(uint16_t u) {
  union { uint32_t i; float f; } v; v.i = ((uint32_t)u) << 16; return v.f;
}
__device__ __forceinline__ uint16_t f2b(float f) {
  uint32_t u = __builtin_bit_cast(uint32_t, f);
  return (uint16_t)((u + 0x7FFFu + ((u >> 16) & 1u)) >> 16);
}

#define GLD16(g, s) __builtin_amdgcn_global_load_lds( \
    (const __attribute__((address_space(1))) void*)(g), \
    (__attribute__((address_space(3))) void*)(s), 16, 0, 0)

// ---------------- prep: f32->bf16 converts + bf16 bias tiles in MFMA C-layout ----------------
__global__ __launch_bounds__(256) void prep(const float* __restrict__ x,
                                            const float* __restrict__ wqv,
                                            const float* __restrict__ pw,
                                            const float* __restrict__ abias,
                                            uint16_t* __restrict__ xb,
                                            uint16_t* __restrict__ wqb,
                                            uint16_t* __restrict__ pwb,
                                            uint16_t* __restrict__ bt2b) {
  const int blk = blockIdx.x;
  const int tid = threadIdx.x;
  if (blk < 3584) {
    const float* in; uint16_t* out; int i;
    if (blk < 2048)      { in = x;   out = xb;  i = blk * 256 + tid; }
    else if (blk < 3072) { in = wqv; out = wqb; i = (blk - 2048) * 256 + tid; }
    else                 { in = pw;  out = pwb; i = (blk - 3072) * 256 + tid; }
    float4 v = ((const float4*)in)[i];
    ushort4 o;
    o.x = f2b(v.x); o.y = f2b(v.y); o.z = f2b(v.z); o.w = f2b(v.w);
    ((ushort4*)out)[i] = o;
  } else {
    __shared__ float rv[63];
    const int blk2 = blk - 3584;           // 0..2015
    const int h = blk2 / 63, d31 = blk2 - h * 63;
    if (tid < 63) rv[tid] = LOG2E * abias[(size_t)(d31 * 63 + tid) * 32 + h];
    __syncthreads();
    const size_t tb = ((size_t)(h * 63 + d31)) << 10;
#pragma unroll
    for (int c = 0; c < 4; ++c) {
      const int idx = c * 256 + tid;       // lane*16 + r
      const int lane = idx >> 4, r = idx & 15;
      const int hi = lane >> 5, ln = lane & 31;
      const int crow = (r & 3) + 8 * (r >> 2) + 4 * hi;
      const int col = 31 + ln - crow;      // 0..62
      bt2b[tb + idx] = f2b(rv[col]);
    }
  }
}

// ---------------- QKV projection GEMM: [4096,512] x [2048,512]^T, 128x64 tiles ----------------
__global__ __launch_bounds__(256) void gemm_qkv(
    const uint16_t* __restrict__ Aop, const uint16_t* __restrict__ Bop,
    uint16_t* __restrict__ qT, uint16_t* __restrict__ ko, uint16_t* __restrict__ vo) {
  const int K = 512;
  __shared__ uint16_t As[2][128 * 32];
  __shared__ uint16_t Bs[2][64 * 32];
  const int tid = threadIdx.x;
  const int lane = tid & 63;
  const int wave = tid >> 6;
  const int am0 = blockIdx.y * 128;
  const int bn0 = blockIdx.x * 64;
  const int wr = wave >> 1, wc = wave & 1;
  const int sc = (tid & 3) << 3;

  auto stage = [&](int buf, int kt) {
    const int k0 = kt << 5;
    GLD16(Aop + (size_t)(am0 + (tid >> 2)) * K + (k0 + sc), &As[buf][tid * 8]);
    GLD16(Aop + (size_t)(am0 + 64 + (tid >> 2)) * K + (k0 + sc), &As[buf][(tid + 256) * 8]);
    GLD16(Bop + (size_t)(bn0 + (tid >> 2)) * K + (k0 + sc), &Bs[buf][tid * 8]);
  };

  f32x4 acc[4][2] = {};
  stage(0, 0);
  asm volatile("s_waitcnt vmcnt(0)" ::: "memory");
  __syncthreads();

  const int fr = lane & 15;
  const int fk = (lane >> 4) << 3;
  int cur = 0;
  for (int kt = 0; kt < 16; ++kt) {
    if (kt + 1 < 16) stage(cur ^ 1, kt + 1);
    bf16x8 af[4], bf_[2];
#pragma unroll
    for (int mi = 0; mi < 4; ++mi)
      af[mi] = *(const bf16x8*)&As[cur][(wr * 64 + mi * 16 + fr) * 32 + fk];
#pragma unroll
    for (int ni = 0; ni < 2; ++ni)
      bf_[ni] = *(const bf16x8*)&Bs[cur][(wc * 32 + ni * 16 + fr) * 32 + fk];
#pragma unroll
    for (int mi = 0; mi < 4; ++mi)
#pragma unroll
      for (int ni = 0; ni < 2; ++ni)
        acc[mi][ni] = __builtin_amdgcn_mfma_f32_16x16x32_bf16(af[mi], bf_[ni], acc[mi][ni], 0, 0, 0);
    asm volatile("s_waitcnt vmcnt(0)" ::: "memory");
    __syncthreads();
    cur ^= 1;
  }

  const int rb = (lane >> 4) << 2;
  const int cl = lane & 15;
  const int b = am0 >> 10;
  const int h = blockIdx.x;
  const int bh = b * 32 + h;
#pragma unroll
  for (int mi = 0; mi < 4; ++mi) {
    const int n0 = (am0 & 1023) + wr * 64 + mi * 16 + rb;
    if (wc == 0) {
      {  // q transposed + pre-scaled
        ushort4 o;
        o.x = f2b(acc[mi][0][0] * QS); o.y = f2b(acc[mi][0][1] * QS);
        o.z = f2b(acc[mi][0][2] * QS); o.w = f2b(acc[mi][0][3] * QS);
        *(ushort4*)&qT[((size_t)(bh * 16 + cl) << 10) + n0] = o;
      }
#pragma unroll
      for (int r = 0; r < 4; ++r)  // k row-major
        ko[((size_t)(bh * 1024 + n0 + r)) * 16 + cl] = f2b(acc[mi][1][r]);
    } else {
#pragma unroll
      for (int ni = 0; ni < 2; ++ni) {  // v channel-major (V^T)
        const int l = h * 32 + ni * 16 + cl;
        ushort4 o;
        o.x = f2b(acc[mi][ni][0]); o.y = f2b(acc[mi][ni][1]);
        o.z = f2b(acc[mi][ni][2]); o.w = f2b(acc[mi][ni][3]);
        *(ushort4*)&vo[((size_t)(b * 1024 + l) << 10) + n0] = o;
      }
    }
  }
}

// ---------------- depthwise 3x3 conv (SAME), channel-major in AND out ----------------
__global__ __launch_bounds__(256) void dwconv3x3(const uint16_t* __restrict__ vimg,
                                                 const float* __restrict__ kw,
                                                 uint16_t* __restrict__ vcv) {
  __shared__ float t[1024];
  const int bl = blockIdx.x;
  const int l = bl & 1023;
  const int tid = threadIdx.x;
  const uint16_t* src = vimg + (size_t)bl * 1024;
  {
    uint2 vv = ((const uint2*)src)[tid];
    t[tid * 4 + 0] = b2f((uint16_t)vv.x);
    t[tid * 4 + 1] = b2f((uint16_t)(vv.x >> 16));
    t[tid * 4 + 2] = b2f((uint16_t)vv.y);
    t[tid * 4 + 3] = b2f((uint16_t)(vv.y >> 16));
  }
  float w[9];
#pragma unroll
  for (int i = 0; i < 9; ++i) w[i] = kw[l * 9 + i];
  __syncthreads();
  uint16_t* dst = vcv + (size_t)bl * 1024;
#pragma unroll
  for (int i = 0; i < 4; ++i) {
    const int p = tid + i * 256;
    const int y = p >> 5, x = p & 31;
    float a = 0.f;
#pragma unroll
    for (int dy = 0; dy < 3; ++dy) {
      const int yy = y + dy - 1;
      if (yy < 0 || yy > 31) continue;
#pragma unroll
      for (int dx = 0; dx < 3; ++dx) {
        const int xx = x + dx - 1;
        if (xx < 0 || xx > 31) continue;
        a += t[yy * 32 + xx] * w[dy * 3 + dx];
      }
    }
    dst[p] = f2b(a);
  }
}

// ---------------- MFMA fused attention + hardswish ----------------
// r18: softmax denominator via MFMA-ones. lacc = mfma(P_frag, ones) gives
// lacc[r] = sum_k P_bf16[q=crow(r,hi),k] in the SAME layout as oacc ->
// normalize is oacc[r]*rcp(lacc[r]) per lane. Deletes 16 lsum VALU adds per
// tile, the end shfl, and the inv_s LDS round-trip; makes num/denom both use
// bf16 P (consistent). Rest identical to r15/r17 structure.
__global__ __launch_bounds__(256, 4) void attn_mfma(
    const uint16_t* __restrict__ qT, const uint16_t* __restrict__ kb,
    const uint16_t* __restrict__ vt, const uint16_t* __restrict__ bt2b,
    uint16_t* __restrict__ hsO) {
  __shared__ __align__(16) uint16_t Ks[2][2][512];
  __shared__ __align__(16) uint16_t Vs[2][2][1024];
  __shared__ __align__(16) uint16_t Bs[7 * 1024];
  const int blk = blockIdx.x;
  const int bh = blk & 127;
  const int qtg = blk >> 7;
  const int b = bh >> 5, h = bh & 31;
  const int tid = threadIdx.x;
  const int wave = tid >> 6, lane = tid & 63;
  const int hi = lane >> 5, ln = lane & 31;

  const int q0 = qtg * 128 + wave * 32;
  const int qi0 = qtg * 4;
  const int qi = qi0 + wave;

  union { ushort u[8]; bf16x8 v; } qu;
#pragma unroll
  for (int j = 0; j < 8; ++j)
    qu.u[j] = qT[((size_t)(bh * 16 + hi * 8 + j) << 10) + q0 + ln];
  const bf16x8 qf = qu.v;

  const u32x4 onesu = {0x3F803F80u, 0x3F803F80u, 0x3F803F80u, 0x3F803F80u};
  const bf16x8 onesv = __builtin_bit_cast(bf16x8, onesu);

  auto stageKV = [&](int buf, int t2) {
    if (tid < 128) {
      const int tile = tid >> 6, j = tid & 63;
      GLD16(kb + ((size_t)bh * 1024 + (t2 + tile) * 32 + (j & 31)) * 16 + ((j >> 5) & 1) * 8,
            &Ks[buf][tile][j * 8]);
    }
    {
      const int tile = tid >> 7, j = tid & 127;
      GLD16(vt + (((size_t)b * 1024 + h * 32 + (j & 31)) << 10) + (t2 + tile) * 32 + ((j >> 5) & 1) * 8 + ((j >> 6) & 1) * 16,
            &Vs[buf][tile][j * 8]);
    }
  };
  auto stageB = [&](int d31, int half) {
    if ((tid >> 7) == half) {
      const int j = tid & 127;
      GLD16(bt2b + (((size_t)h * 63 + d31) << 10) + (j & 63) * 16 + ((j >> 6) & 1) * 8,
            &Bs[(d31 % 7) * 1024 + j * 8]);
    }
  };

  stageKV(0, 0);
  stageB(qi0 + 30, 0); stageB(qi0 + 31, 1);
  stageB(qi0 + 32, 0); stageB(qi0 + 33, 1);
  stageB(qi0 + 34, 0);
  __syncthreads();

  f32x16 oacc = {};
  f32x16 lacc = {};
  int cur = 0;
  int slotA = (qi + 31) % 7;

#define COMPUTE(kf, ca, cb, vf0, vf1) do {                            \
    f32x16 cc;                                                        \
    _Pragma("unroll")                                                 \
    for (int j = 0; j < 4; ++j) {                                     \
      const uint32_t ua = ca[j], ub = cb[j];                          \
      cc[2 * j]     = __builtin_bit_cast(float, ua << 16);            \
      cc[2 * j + 1] = __builtin_bit_cast(float, ua & 0xFFFF0000u);    \
      cc[8 + 2 * j]     = __builtin_bit_cast(float, ub << 16);        \
      cc[8 + 2 * j + 1] = __builtin_bit_cast(float, ub & 0xFFFF0000u);\
    }                                                                 \
    const f32x16 s = __builtin_amdgcn_mfma_f32_32x32x16_bf16(kf, qf, cc, 0, 0, 0); \
    float p[16];                                                      \
    _Pragma("unroll")                                                 \
    for (int r = 0; r < 16; ++r) p[r] = __builtin_amdgcn_exp2f(s[r]); \
    uint32_t w0, w1, w2, w3, w4, w5, w6, w7;                          \
    w0 = __builtin_amdgcn_perm(__builtin_bit_cast(uint32_t, p[1]),  __builtin_bit_cast(uint32_t, p[0]),  0x07060302u); \
    w1 = __builtin_amdgcn_perm(__builtin_bit_cast(uint32_t, p[3]),  __builtin_bit_cast(uint32_t, p[2]),  0x07060302u); \
    w2 = __builtin_amdgcn_perm(__builtin_bit_cast(uint32_t, p[5]),  __builtin_bit_cast(uint32_t, p[4]),  0x07060302u); \
    w3 = __builtin_amdgcn_perm(__builtin_bit_cast(uint32_t, p[7]),  __builtin_bit_cast(uint32_t, p[6]),  0x07060302u); \
    w4 = __builtin_amdgcn_perm(__builtin_bit_cast(uint32_t, p[9]),  __builtin_bit_cast(uint32_t, p[8]),  0x07060302u); \
    w5 = __builtin_amdgcn_perm(__builtin_bit_cast(uint32_t, p[11]), __builtin_bit_cast(uint32_t, p[10]), 0x07060302u); \
    w6 = __builtin_amdgcn_perm(__builtin_bit_cast(uint32_t, p[13]), __builtin_bit_cast(uint32_t, p[12]), 0x07060302u); \
    w7 = __builtin_amdgcn_perm(__builtin_bit_cast(uint32_t, p[15]), __builtin_bit_cast(uint32_t, p[14]), 0x07060302u); \
    asm("v_permlane32_swap_b32 %0, %1" : "+v"(w0), "+v"(w2));         \
    asm("v_permlane32_swap_b32 %0, %1" : "+v"(w1), "+v"(w3));         \
    asm("v_permlane32_swap_b32 %0, %1" : "+v"(w4), "+v"(w6));         \
    asm("v_permlane32_swap_b32 %0, %1" : "+v"(w5), "+v"(w7));         \
    const u32x4 a0u = {w0, w1, w2, w3};                               \
    const u32x4 a1u = {w4, w5, w6, w7};                               \
    oacc = __builtin_amdgcn_mfma_f32_32x32x16_bf16(                   \
        __builtin_bit_cast(bf16x8, a0u), vf0, oacc, 0, 0, 0);         \
    oacc = __builtin_amdgcn_mfma_f32_32x32x16_bf16(                   \
        __builtin_bit_cast(bf16x8, a1u), vf1, oacc, 0, 0, 0);         \
    lacc = __builtin_amdgcn_mfma_f32_32x32x16_bf16(                   \
        __builtin_bit_cast(bf16x8, a0u), onesv, lacc, 0, 0, 0);       \
    lacc = __builtin_amdgcn_mfma_f32_32x32x16_bf16(                   \
        __builtin_bit_cast(bf16x8, a1u), onesv, lacc, 0, 0, 0);       \
  } while (0)

  for (int s = 0; s < 16; ++s) {
    if (s < 15) {
      stageKV(cur ^ 1, 2 * s + 2);
      stageB(qi0 + 29 - 2 * s, 0);
      stageB(qi0 + 28 - 2 * s, 1);
    }
    const int slotB = slotA ? slotA - 1 : 6;
    __builtin_amdgcn_s_setprio(1);
    {  // tile 2s
      const bf16x8 kf  = *(const bf16x8*)&Ks[cur][0][lane * 8];
      const bf16x8 vf0 = *(const bf16x8*)&Vs[cur][0][lane * 8];
      const bf16x8 vf1 = *(const bf16x8*)&Vs[cur][0][512 + lane * 8];
      const u32x4 ca = *(const u32x4*)&Bs[slotA * 1024 + lane * 8];
      const u32x4 cb = *(const u32x4*)&Bs[slotA * 1024 + 512 + lane * 8];
      COMPUTE(kf, ca, cb, vf0, vf1);
    }
    {  // tile 2s+1
      const bf16x8 kf  = *(const bf16x8*)&Ks[cur][1][lane * 8];
      const bf16x8 vf0 = *(const bf16x8*)&Vs[cur][1][lane * 8];
      const bf16x8 vf1 = *(const bf16x8*)&Vs[cur][1][512 + lane * 8];
      const u32x4 ca = *(const u32x4*)&Bs[slotB * 1024 + lane * 8];
      const u32x4 cb = *(const u32x4*)&Bs[slotB * 1024 + 512 + lane * 8];
      COMPUTE(kf, ca, cb, vf0, vf1);
    }
    __builtin_amdgcn_s_setprio(0);
    __syncthreads();
    cur ^= 1;
    slotA = (slotA >= 2) ? slotA - 2 : slotA + 5;
  }
#undef COMPUTE

  const int ROWS[16] = {0,1,2,3,8,9,10,11,16,17,18,19,24,25,26,27};
#pragma unroll
  for (int r = 0; r < 16; ++r) {
    const int row = ROWS[r] + 4 * hi;
    const float o = oacc[r] * __builtin_amdgcn_rcpf(lacc[r]);
    const float hs = o * fminf(fmaxf(o + 3.f, 0.f), 6.f) * (1.f / 6.f);
    hsO[((size_t)(b * 1024 + q0 + row) << 10) + h * 32 + ln] = f2b(hs);
  }
}

// ---------------- output projection GEMM: [4096,1024] x [512,1024]^T, BK=64 ----------------
__global__ __launch_bounds__(256) void gemm_proj(
    const uint16_t* __restrict__ Aop, const uint16_t* __restrict__ Bop,
    float* __restrict__ Cout, const float* __restrict__ bias) {
  const int K = 1024;
  __shared__ uint16_t As[2][64 * 64];
  __shared__ uint16_t Bs[2][64 * 64];
  const int tid = threadIdx.x;
  const int lane = tid & 63;
  const int wave = tid >> 6;
  const int am0 = blockIdx.y * 64;
  const int bn0 = blockIdx.x * 64;
  const int m_off = (wave >> 1) * 32;
  const int n_off = (wave & 1) * 32;
  const int sr = tid >> 3;
  const int sc = (tid & 7) << 3;

  auto stage = [&](int buf, int kt) {
    const int k0 = kt << 6;
    GLD16(Aop + (size_t)(am0 + sr) * K + (k0 + sc), &As[buf][tid * 8]);
    GLD16(Aop + (size_t)(am0 + 32 + sr) * K + (k0 + sc), &As[buf][(tid + 256) * 8]);
    GLD16(Bop + (size_t)(bn0 + sr) * K + (k0 + sc), &Bs[buf][tid * 8]);
    GLD16(Bop + (size_t)(bn0 + 32 + sr) * K + (k0 + sc), &Bs[buf][(tid + 256) * 8]);
  };

  f32x4 acc[2][2] = {};
  stage(0, 0);
  asm volatile("s_waitcnt vmcnt(0)" ::: "memory");
  __syncthreads();

  const int fr = lane & 15;
  const int fk = (lane >> 4) << 3;
  int cur = 0;
  for (int kt = 0; kt < 16; ++kt) {
    if (kt + 1 < 16) stage(cur ^ 1, kt + 1);
#pragma unroll
    for (int kk = 0; kk < 2; ++kk) {
      bf16x8 af[2], bf_[2];
#pragma unroll
      for (int mi = 0; mi < 2; ++mi)
        af[mi] = *(const bf16x8*)&As[cur][(m_off + mi * 16 + fr) * 64 + kk * 32 + fk];
#pragma unroll
      for (int ni = 0; ni < 2; ++ni)
        bf_[ni] = *(const bf16x8*)&Bs[cur][(n_off + ni * 16 + fr) * 64 + kk * 32 + fk];
#pragma unroll
      for (int mi = 0; mi < 2; ++mi)
#pragma unroll
        for (int ni = 0; ni < 2; ++ni)
          acc[mi][ni] = __builtin_amdgcn_mfma_f32_16x16x32_bf16(af[mi], bf_[ni], acc[mi][ni], 0, 0, 0);
    }
    asm volatile("s_waitcnt vmcnt(0)" ::: "memory");
    __syncthreads();
    cur ^= 1;
  }

  const int rb = (lane >> 4) << 2;
  const int cl = lane & 15;
#pragma unroll
  for (int mi = 0; mi < 2; ++mi)
#pragma unroll
    for (int ni = 0; ni < 2; ++ni) {
      const int cg = bn0 + n_off + ni * 16 + cl;
#pragma unroll
      for (int r = 0; r < 4; ++r) {
        const int rg = am0 + m_off + mi * 16 + rb + r;
        Cout[(size_t)rg * 512 + cg] = acc[mi][ni][r] + bias[cg];
      }
    }
}

// ---------------- launch ----------------
extern "C" void kernel_launch(void* const* d_in, const int* in_sizes, int n_in,
                              void* d_out, int out_size, void* d_ws, size_t ws_size,
                              hipStream_t stream) {
  const float* x      = (const float*)d_in[0];
  const float* w_qkv  = (const float*)d_in[1];
  const float* dwk    = (const float*)d_in[2];
  const float* abias  = (const float*)d_in[3];
  const float* pw     = (const float*)d_in[4];
  const float* pb     = (const float*)d_in[5];
  float* out = (float*)d_out;

  char* ws = (char*)d_ws;
  uint16_t* xb   = (uint16_t*)(ws);                 // 4 MB
  uint16_t* wqb  = (uint16_t*)(ws + (4ull << 20));  // 2 MB
  uint16_t* pwb  = (uint16_t*)(ws + (6ull << 20));  // 1 MB
  uint16_t* qT   = (uint16_t*)(ws + (7ull << 20));  // 4 MB
  uint16_t* kbuf = (uint16_t*)(ws + (11ull << 20)); // 4 MB
  uint16_t* vimg = (uint16_t*)(ws + (15ull << 20)); // 8 MB (reused as hsO)
  uint16_t* vcv  = (uint16_t*)(ws + (23ull << 20)); // 8 MB (channel-major = V^T)
  uint16_t* bt2b = (uint16_t*)(ws + (31ull << 20)); // 4 MB bf16 bias tiles
  uint16_t* hsO  = vimg;

  prep<<<5600, 256, 0, stream>>>(x, w_qkv, pw, abias, xb, wqb, pwb, bt2b);
  gemm_qkv<<<dim3(32, 32), 256, 0, stream>>>(xb, wqb, qT, kbuf, vimg);
  dwconv3x3<<<4096, 256, 0, stream>>>(vimg, dwk, vcv);
  attn_mfma<<<1024, 256, 0, stream>>>(qT, kbuf, vcv, bt2b, hsO);
  gemm_proj<<<dim3(8, 64), 256, 0, stream>>>(hsO, pwb, out, pb);
}

// Round 19
// 82.538 us; speedup vs baseline: 1.0644x; 1.0173x over previous
//
#include <hip/hip_runtime.h>
#include <stdint.h>

#define HEADS 32
#define HW_N 1024
#define QS 0.36067376022224085f   // 0.25 * log2(e)
#define LOG2E 1.4426950408889634f

typedef __attribute__((ext_vector_type(8))) __bf16 bf16x8;
typedef __attribute__((ext_vector_type(4))) float f32x4;
typedef __attribute__((ext_vector_type(16))) float f32x16;
typedef __attribute__((ext_vector_type(4))) uint32_t u32x4;

__device__ __forceinline__ float b2f(uint16_t u) {
  union { uint32_t i; float f; } v; v.i = ((uint32_t)u) << 16; return v.f;
}
__device__ __forceinline__ uint16_t f2b(float f) {
  uint32_t u = __builtin_bit_cast(uint32_t, f);
  return (uint16_t)((u + 0x7FFFu + ((u >> 16) & 1u)) >> 16);
}

#define GLD16(g, s) __builtin_amdgcn_global_load_lds( \
    (const __attribute__((address_space(1))) void*)(g), \
    (__attribute__((address_space(3))) void*)(s), 16, 0, 0)

// ---------------- prep: f32->bf16 converts + bf16 bias tiles in MFMA C-layout ----------------
// r19: bias blocks permuted so tile (h,d31) is produced on XCD h%8 — the same
// XCD that attn's readers of h live on (attn blk%8 = bh%8 = h%8).
__global__ __launch_bounds__(256) void prep(const float* __restrict__ x,
                                            const float* __restrict__ wqv,
                                            const float* __restrict__ pw,
                                            const float* __restrict__ abias,
                                            uint16_t* __restrict__ xb,
                                            uint16_t* __restrict__ wqb,
                                            uint16_t* __restrict__ pwb,
                                            uint16_t* __restrict__ bt2b) {
  const int blk = blockIdx.x;
  const int tid = threadIdx.x;
  if (blk < 3584) {
    const float* in; uint16_t* out; int i;
    if (blk < 2048)      { in = x;   out = xb;  i = blk * 256 + tid; }
    else if (blk < 3072) { in = wqv; out = wqb; i = (blk - 2048) * 256 + tid; }
    else                 { in = pw;  out = pwb; i = (blk - 3072) * 256 + tid; }
    float4 v = ((const float4*)in)[i];
    ushort4 o;
    o.x = f2b(v.x); o.y = f2b(v.y); o.z = f2b(v.z); o.w = f2b(v.w);
    ((ushort4*)out)[i] = o;
  } else {
    __shared__ float rv[63];
    const int j = blk - 3584;            // 0..2015 ; (3584+j)%8 == j%8
    const int key = j & 7, idx = j >> 3; // idx 0..251 = 4*63
    const int h = key + 8 * (idx / 63);  // h%8 == key == XCD
    const int d31 = idx % 63;
    if (tid < 63) rv[tid] = LOG2E * abias[(size_t)(d31 * 63 + tid) * 32 + h];
    __syncthreads();
    const size_t tb = ((size_t)(h * 63 + d31)) << 10;
#pragma unroll
    for (int c = 0; c < 4; ++c) {
      const int idx2 = c * 256 + tid;      // lane*16 + r
      const int lane = idx2 >> 4, r = idx2 & 15;
      const int hi = lane >> 5, ln = lane & 31;
      const int crow = (r & 3) + 8 * (r >> 2) + 4 * hi;
      const int col = 31 + ln - crow;      // 0..62
      bt2b[tb + idx2] = f2b(rv[col]);
    }
  }
}

// ---------------- QKV projection GEMM: [4096,512] x [2048,512]^T, 128x64 tiles ----------------
__global__ __launch_bounds__(256) void gemm_qkv(
    const uint16_t* __restrict__ Aop, const uint16_t* __restrict__ Bop,
    uint16_t* __restrict__ qT, uint16_t* __restrict__ ko, uint16_t* __restrict__ vo) {
  const int K = 512;
  __shared__ uint16_t As[2][128 * 32];
  __shared__ uint16_t Bs[2][64 * 32];
  const int tid = threadIdx.x;
  const int lane = tid & 63;
  const int wave = tid >> 6;
  const int am0 = blockIdx.y * 128;
  const int bn0 = blockIdx.x * 64;
  const int wr = wave >> 1, wc = wave & 1;
  const int sc = (tid & 3) << 3;

  auto stage = [&](int buf, int kt) {
    const int k0 = kt << 5;
    GLD16(Aop + (size_t)(am0 + (tid >> 2)) * K + (k0 + sc), &As[buf][tid * 8]);
    GLD16(Aop + (size_t)(am0 + 64 + (tid >> 2)) * K + (k0 + sc), &As[buf][(tid + 256) * 8]);
    GLD16(Bop + (size_t)(bn0 + (tid >> 2)) * K + (k0 + sc), &Bs[buf][tid * 8]);
  };

  f32x4 acc[4][2] = {};
  stage(0, 0);
  asm volatile("s_waitcnt vmcnt(0)" ::: "memory");
  __syncthreads();

  const int fr = lane & 15;
  const int fk = (lane >> 4) << 3;
  int cur = 0;
  for (int kt = 0; kt < 16; ++kt) {
    if (kt + 1 < 16) stage(cur ^ 1, kt + 1);
    bf16x8 af[4], bf_[2];
#pragma unroll
    for (int mi = 0; mi < 4; ++mi)
      af[mi] = *(const bf16x8*)&As[cur][(wr * 64 + mi * 16 + fr) * 32 + fk];
#pragma unroll
    for (int ni = 0; ni < 2; ++ni)
      bf_[ni] = *(const bf16x8*)&Bs[cur][(wc * 32 + ni * 16 + fr) * 32 + fk];
#pragma unroll
    for (int mi = 0; mi < 4; ++mi)
#pragma unroll
      for (int ni = 0; ni < 2; ++ni)
        acc[mi][ni] = __builtin_amdgcn_mfma_f32_16x16x32_bf16(af[mi], bf_[ni], acc[mi][ni], 0, 0, 0);
    asm volatile("s_waitcnt vmcnt(0)" ::: "memory");
    __syncthreads();
    cur ^= 1;
  }

  const int rb = (lane >> 4) << 2;
  const int cl = lane & 15;
  const int b = am0 >> 10;
  const int h = blockIdx.x;
  const int bh = b * 32 + h;
#pragma unroll
  for (int mi = 0; mi < 4; ++mi) {
    const int n0 = (am0 & 1023) + wr * 64 + mi * 16 + rb;
    if (wc == 0) {
      {  // q transposed + pre-scaled
        ushort4 o;
        o.x = f2b(acc[mi][0][0] * QS); o.y = f2b(acc[mi][0][1] * QS);
        o.z = f2b(acc[mi][0][2] * QS); o.w = f2b(acc[mi][0][3] * QS);
        *(ushort4*)&qT[((size_t)(bh * 16 + cl) << 10) + n0] = o;
      }
#pragma unroll
      for (int r = 0; r < 4; ++r)  // k row-major
        ko[((size_t)(bh * 1024 + n0 + r)) * 16 + cl] = f2b(acc[mi][1][r]);
    } else {
#pragma unroll
      for (int ni = 0; ni < 2; ++ni) {  // v channel-major (V^T)
        const int l = h * 32 + ni * 16 + cl;
        ushort4 o;
        o.x = f2b(acc[mi][ni][0]); o.y = f2b(acc[mi][ni][1]);
        o.z = f2b(acc[mi][ni][2]); o.w = f2b(acc[mi][ni][3]);
        *(ushort4*)&vo[((size_t)(b * 1024 + l) << 10) + n0] = o;
      }
    }
  }
}

// ---------------- depthwise 3x3 conv (SAME), channel-major in AND out ----------------
// r19: grid permuted so channel l of batch b is processed on XCD h%8
// (h = l>>5) — matching vimg's producer (gemm_qkv, bx=h) and vcv's consumer
// (attn, blk%8 = h%8). Pure relabeling; work identical.
__global__ __launch_bounds__(256) void dwconv3x3(const uint16_t* __restrict__ vimg,
                                                 const float* __restrict__ kw,
                                                 uint16_t* __restrict__ vcv) {
  __shared__ float t[1024];
  const int m = blockIdx.x;
  const int key = m & 7, idx = m >> 3;   // idx 0..511
  const int d = idx & 31, h_sub = (idx >> 5) & 3, b = idx >> 7;
  const int h = key + 8 * h_sub;
  const int l = h * 32 + d;
  const int bl = b * 1024 + l;
  const int tid = threadIdx.x;
  const uint16_t* src = vimg + (size_t)bl * 1024;
  {
    uint2 vv = ((const uint2*)src)[tid];
    t[tid * 4 + 0] = b2f((uint16_t)vv.x);
    t[tid * 4 + 1] = b2f((uint16_t)(vv.x >> 16));
    t[tid * 4 + 2] = b2f((uint16_t)vv.y);
    t[tid * 4 + 3] = b2f((uint16_t)(vv.y >> 16));
  }
  float w[9];
#pragma unroll
  for (int i = 0; i < 9; ++i) w[i] = kw[l * 9 + i];
  __syncthreads();
  uint16_t* dst = vcv + (size_t)bl * 1024;
#pragma unroll
  for (int i = 0; i < 4; ++i) {
    const int p = tid + i * 256;
    const int y = p >> 5, x = p & 31;
    float a = 0.f;
#pragma unroll
    for (int dy = 0; dy < 3; ++dy) {
      const int yy = y + dy - 1;
      if (yy < 0 || yy > 31) continue;
#pragma unroll
      for (int dx = 0; dx < 3; ++dx) {
        const int xx = x + dx - 1;
        if (xx < 0 || xx > 31) continue;
        a += t[yy * 32 + xx] * w[dy * 3 + dx];
      }
    }
    dst[p] = f2b(a);
  }
}

// ---------------- MFMA fused attention + hardswish ----------------
// r18 structure (2-tile superstep, LDS-staged K/V/bias, 7-slot ring,
// MFMA-ones denominator, setprio). All inputs now produced XCD-locally.
__global__ __launch_bounds__(256, 4) void attn_mfma(
    const uint16_t* __restrict__ qT, const uint16_t* __restrict__ kb,
    const uint16_t* __restrict__ vt, const uint16_t* __restrict__ bt2b,
    uint16_t* __restrict__ hsO) {
  __shared__ __align__(16) uint16_t Ks[2][2][512];
  __shared__ __align__(16) uint16_t Vs[2][2][1024];
  __shared__ __align__(16) uint16_t Bs[7 * 1024];
  const int blk = blockIdx.x;
  const int bh = blk & 127;
  const int qtg = blk >> 7;
  const int b = bh >> 5, h = bh & 31;
  const int tid = threadIdx.x;
  const int wave = tid >> 6, lane = tid & 63;
  const int hi = lane >> 5, ln = lane & 31;

  const int q0 = qtg * 128 + wave * 32;
  const int qi0 = qtg * 4;
  const int qi = qi0 + wave;

  union { ushort u[8]; bf16x8 v; } qu;
#pragma unroll
  for (int j = 0; j < 8; ++j)
    qu.u[j] = qT[((size_t)(bh * 16 + hi * 8 + j) << 10) + q0 + ln];
  const bf16x8 qf = qu.v;

  const u32x4 onesu = {0x3F803F80u, 0x3F803F80u, 0x3F803F80u, 0x3F803F80u};
  const bf16x8 onesv = __builtin_bit_cast(bf16x8, onesu);

  auto stageKV = [&](int buf, int t2) {
    if (tid < 128) {
      const int tile = tid >> 6, j = tid & 63;
      GLD16(kb + ((size_t)bh * 1024 + (t2 + tile) * 32 + (j & 31)) * 16 + ((j >> 5) & 1) * 8,
            &Ks[buf][tile][j * 8]);
    }
    {
      const int tile = tid >> 7, j = tid & 127;
      GLD16(vt + (((size_t)b * 1024 + h * 32 + (j & 31)) << 10) + (t2 + tile) * 32 + ((j >> 5) & 1) * 8 + ((j >> 6) & 1) * 16,
            &Vs[buf][tile][j * 8]);
    }
  };
  auto stageB = [&](int d31, int half) {
    if ((tid >> 7) == half) {
      const int j = tid & 127;
      GLD16(bt2b + (((size_t)h * 63 + d31) << 10) + (j & 63) * 16 + ((j >> 6) & 1) * 8,
            &Bs[(d31 % 7) * 1024 + j * 8]);
    }
  };

  stageKV(0, 0);
  stageB(qi0 + 30, 0); stageB(qi0 + 31, 1);
  stageB(qi0 + 32, 0); stageB(qi0 + 33, 1);
  stageB(qi0 + 34, 0);
  __syncthreads();

  f32x16 oacc = {};
  f32x16 lacc = {};
  int cur = 0;
  int slotA = (qi + 31) % 7;

#define COMPUTE(kf, ca, cb, vf0, vf1) do {                            \
    f32x16 cc;                                                        \
    _Pragma("unroll")                                                 \
    for (int j = 0; j < 4; ++j) {                                     \
      const uint32_t ua = ca[j], ub = cb[j];                          \
      cc[2 * j]     = __builtin_bit_cast(float, ua << 16);            \
      cc[2 * j + 1] = __builtin_bit_cast(float, ua & 0xFFFF0000u);    \
      cc[8 + 2 * j]     = __builtin_bit_cast(float, ub << 16);        \
      cc[8 + 2 * j + 1] = __builtin_bit_cast(float, ub & 0xFFFF0000u);\
    }                                                                 \
    const f32x16 s = __builtin_amdgcn_mfma_f32_32x32x16_bf16(kf, qf, cc, 0, 0, 0); \
    float p[16];                                                      \
    _Pragma("unroll")                                                 \
    for (int r = 0; r < 16; ++r) p[r] = __builtin_amdgcn_exp2f(s[r]); \
    uint32_t w0, w1, w2, w3, w4, w5, w6, w7;                          \
    w0 = __builtin_amdgcn_perm(__builtin_bit_cast(uint32_t, p[1]),  __builtin_bit_cast(uint32_t, p[0]),  0x07060302u); \
    w1 = __builtin_amdgcn_perm(__builtin_bit_cast(uint32_t, p[3]),  __builtin_bit_cast(uint32_t, p[2]),  0x07060302u); \
    w2 = __builtin_amdgcn_perm(__builtin_bit_cast(uint32_t, p[5]),  __builtin_bit_cast(uint32_t, p[4]),  0x07060302u); \
    w3 = __builtin_amdgcn_perm(__builtin_bit_cast(uint32_t, p[7]),  __builtin_bit_cast(uint32_t, p[6]),  0x07060302u); \
    w4 = __builtin_amdgcn_perm(__builtin_bit_cast(uint32_t, p[9]),  __builtin_bit_cast(uint32_t, p[8]),  0x07060302u); \
    w5 = __builtin_amdgcn_perm(__builtin_bit_cast(uint32_t, p[11]), __builtin_bit_cast(uint32_t, p[10]), 0x07060302u); \
    w6 = __builtin_amdgcn_perm(__builtin_bit_cast(uint32_t, p[13]), __builtin_bit_cast(uint32_t, p[12]), 0x07060302u); \
    w7 = __builtin_amdgcn_perm(__builtin_bit_cast(uint32_t, p[15]), __builtin_bit_cast(uint32_t, p[14]), 0x07060302u); \
    asm("v_permlane32_swap_b32 %0, %1" : "+v"(w0), "+v"(w2));         \
    asm("v_permlane32_swap_b32 %0, %1" : "+v"(w1), "+v"(w3));         \
    asm("v_permlane32_swap_b32 %0, %1" : "+v"(w4), "+v"(w6));         \
    asm("v_permlane32_swap_b32 %0, %1" : "+v"(w5), "+v"(w7));         \
    const u32x4 a0u = {w0, w1, w2, w3};                               \
    const u32x4 a1u = {w4, w5, w6, w7};                               \
    oacc = __builtin_amdgcn_mfma_f32_32x32x16_bf16(                   \
        __builtin_bit_cast(bf16x8, a0u), vf0, oacc, 0, 0, 0);         \
    oacc = __builtin_amdgcn_mfma_f32_32x32x16_bf16(                   \
        __builtin_bit_cast(bf16x8, a1u), vf1, oacc, 0, 0, 0);         \
    lacc = __builtin_amdgcn_mfma_f32_32x32x16_bf16(                   \
        __builtin_bit_cast(bf16x8, a0u), onesv, lacc, 0, 0, 0);       \
    lacc = __builtin_amdgcn_mfma_f32_32x32x16_bf16(                   \
        __builtin_bit_cast(bf16x8, a1u), onesv, lacc, 0, 0, 0);       \
  } while (0)

  for (int s = 0; s < 16; ++s) {
    if (s < 15) {
      stageKV(cur ^ 1, 2 * s + 2);
      stageB(qi0 + 29 - 2 * s, 0);
      stageB(qi0 + 28 - 2 * s, 1);
    }
    const int slotB = slotA ? slotA - 1 : 6;
    __builtin_amdgcn_s_setprio(1);
    {  // tile 2s
      const bf16x8 kf  = *(const bf16x8*)&Ks[cur][0][lane * 8];
      const bf16x8 vf0 = *(const bf16x8*)&Vs[cur][0][lane * 8];
      const bf16x8 vf1 = *(const bf16x8*)&Vs[cur][0][512 + lane * 8];
      const u32x4 ca = *(const u32x4*)&Bs[slotA * 1024 + lane * 8];
      const u32x4 cb = *(const u32x4*)&Bs[slotA * 1024 + 512 + lane * 8];
      COMPUTE(kf, ca, cb, vf0, vf1);
    }
    {  // tile 2s+1
      const bf16x8 kf  = *(const bf16x8*)&Ks[cur][1][lane * 8];
      const bf16x8 vf0 = *(const bf16x8*)&Vs[cur][1][lane * 8];
      const bf16x8 vf1 = *(const bf16x8*)&Vs[cur][1][512 + lane * 8];
      const u32x4 ca = *(const u32x4*)&Bs[slotB * 1024 + lane * 8];
      const u32x4 cb = *(const u32x4*)&Bs[slotB * 1024 + 512 + lane * 8];
      COMPUTE(kf, ca, cb, vf0, vf1);
    }
    __builtin_amdgcn_s_setprio(0);
    __syncthreads();
    cur ^= 1;
    slotA = (slotA >= 2) ? slotA - 2 : slotA + 5;
  }
#undef COMPUTE

  const int ROWS[16] = {0,1,2,3,8,9,10,11,16,17,18,19,24,25,26,27};
#pragma unroll
  for (int r = 0; r < 16; ++r) {
    const int row = ROWS[r] + 4 * hi;
    const float o = oacc[r] * __builtin_amdgcn_rcpf(lacc[r]);
    const float hs = o * fminf(fmaxf(o + 3.f, 0.f), 6.f) * (1.f / 6.f);
    hsO[((size_t)(b * 1024 + q0 + row) << 10) + h * 32 + ln] = f2b(hs);
  }
}

// ---------------- output projection GEMM: [4096,1024] x [512,1024]^T, BK=64 ----------------
__global__ __launch_bounds__(256) void gemm_proj(
    const uint16_t* __restrict__ Aop, const uint16_t* __restrict__ Bop,
    float* __restrict__ Cout, const float* __restrict__ bias) {
  const int K = 1024;
  __shared__ uint16_t As[2][64 * 64];
  __shared__ uint16_t Bs[2][64 * 64];
  const int tid = threadIdx.x;
  const int lane = tid & 63;
  const int wave = tid >> 6;
  const int am0 = blockIdx.y * 64;
  const int bn0 = blockIdx.x * 64;
  const int m_off = (wave >> 1) * 32;
  const int n_off = (wave & 1) * 32;
  const int sr = tid >> 3;
  const int sc = (tid & 7) << 3;

  auto stage = [&](int buf, int kt) {
    const int k0 = kt << 6;
    GLD16(Aop + (size_t)(am0 + sr) * K + (k0 + sc), &As[buf][tid * 8]);
    GLD16(Aop + (size_t)(am0 + 32 + sr) * K + (k0 + sc), &As[buf][(tid + 256) * 8]);
    GLD16(Bop + (size_t)(bn0 + sr) * K + (k0 + sc), &Bs[buf][tid * 8]);
    GLD16(Bop + (size_t)(bn0 + 32 + sr) * K + (k0 + sc), &Bs[buf][(tid + 256) * 8]);
  };

  f32x4 acc[2][2] = {};
  stage(0, 0);
  asm volatile("s_waitcnt vmcnt(0)" ::: "memory");
  __syncthreads();

  const int fr = lane & 15;
  const int fk = (lane >> 4) << 3;
  int cur = 0;
  for (int kt = 0; kt < 16; ++kt) {
    if (kt + 1 < 16) stage(cur ^ 1, kt + 1);
#pragma unroll
    for (int kk = 0; kk < 2; ++kk) {
      bf16x8 af[2], bf_[2];
#pragma unroll
      for (int mi = 0; mi < 2; ++mi)
        af[mi] = *(const bf16x8*)&As[cur][(m_off + mi * 16 + fr) * 64 + kk * 32 + fk];
#pragma unroll
      for (int ni = 0; ni < 2; ++ni)
        bf_[ni] = *(const bf16x8*)&Bs[cur][(n_off + ni * 16 + fr) * 64 + kk * 32 + fk];
#pragma unroll
      for (int mi = 0; mi < 2; ++mi)
#pragma unroll
        for (int ni = 0; ni < 2; ++ni)
          acc[mi][ni] = __builtin_amdgcn_mfma_f32_16x16x32_bf16(af[mi], bf_[ni], acc[mi][ni], 0, 0, 0);
    }
    asm volatile("s_waitcnt vmcnt(0)" ::: "memory");
    __syncthreads();
    cur ^= 1;
  }

  const int rb = (lane >> 4) << 2;
  const int cl = lane & 15;
#pragma unroll
  for (int mi = 0; mi < 2; ++mi)
#pragma unroll
    for (int ni = 0; ni < 2; ++ni) {
      const int cg = bn0 + n_off + ni * 16 + cl;
#pragma unroll
      for (int r = 0; r < 4; ++r) {
        const int rg = am0 + m_off + mi * 16 + rb + r;
        Cout[(size_t)rg * 512 + cg] = acc[mi][ni][r] + bias[cg];
      }
    }
}

// ---------------- launch ----------------
extern "C" void kernel_launch(void* const* d_in, const int* in_sizes, int n_in,
                              void* d_out, int out_size, void* d_ws, size_t ws_size,
                              hipStream_t stream) {
  const float* x      = (const float*)d_in[0];
  const float* w_qkv  = (const float*)d_in[1];
  const float* dwk    = (const float*)d_in[2];
  const float* abias  = (const float*)d_in[3];
  const float* pw     = (const float*)d_in[4];
  const float* pb     = (const float*)d_in[5];
  float* out = (float*)d_out;

  char* ws = (char*)d_ws;
  uint16_t* xb   = (uint16_t*)(ws);                 // 4 MB
  uint16_t* wqb  = (uint16_t*)(ws + (4ull << 20));  // 2 MB
  uint16_t* pwb  = (uint16_t*)(ws + (6ull << 20));  // 1 MB
  uint16_t* qT   = (uint16_t*)(ws + (7ull << 20));  // 4 MB
  uint16_t* kbuf = (uint16_t*)(ws + (11ull << 20)); // 4 MB
  uint16_t* vimg = (uint16_t*)(ws + (15ull << 20)); // 8 MB (reused as hsO)
  uint16_t* vcv  = (uint16_t*)(ws + (23ull << 20)); // 8 MB (channel-major = V^T)
  uint16_t* bt2b = (uint16_t*)(ws + (31ull << 20)); // 4 MB bf16 bias tiles
  uint16_t* hsO  = vimg;

  prep<<<5600, 256, 0, stream>>>(x, w_qkv, pw, abias, xb, wqb, pwb, bt2b);
  gemm_qkv<<<dim3(32, 32), 256, 0, stream>>>(xb, wqb, qT, kbuf, vimg);
  dwconv3x3<<<4096, 256, 0, stream>>>(vimg, dwk, vcv);
  attn_mfma<<<1024, 256, 0, stream>>>(qT, kbuf, vcv, bt2b, hsO);
  gemm_proj<<<dim3(8, 64), 256, 0, stream>>>(hsO, pwb, out, pb);
}